// Round 1
// baseline (62182.275 us; speedup 1.0000x reference)
//
#include <hip/hip_runtime.h>
#include <math.h>

#define BB 64
#define TT 128
#define VV 10000
#define EE 300
#define HH 1024
#define TM1 127
#define G4 4096

// ---------------- utility: zero a float region ----------------
__global__ void zero_kernel(float* __restrict__ p, int n) {
    int i = blockIdx.x * blockDim.x + threadIdx.x;
    if (i < n) p[i] = 0.0f;
}

// ---------------- embedding gather ----------------
// X[(t*64+b)*300 + e] = wordvec[sent[b*128+t]*300 + e], t in [0,127)
__global__ void embed_kernel(const int* __restrict__ sent,
                             const float* __restrict__ wordvec,
                             float* __restrict__ X) {
    int bi = blockIdx.x;          // 0..8127 = t*64+b
    int t = bi >> 6;
    int b = bi & 63;
    int row = sent[b * TT + t];
    const float* src = wordvec + (long)row * EE;
    float* dst = X + (long)bi * EE;
    for (int e = threadIdx.x; e < EE; e += blockDim.x) dst[e] = src[e];
}

// ---------------- fused LSTM step ----------------
// gates = x @ w_ih + h_prev @ w_hh + bias ; LSTM elementwise ; writes h_out, c (in place), optional h_store
// grid: 256 blocks, block jb owns hidden cols j0..j0+3 (all 4 gates). 256 threads.
__global__ __launch_bounds__(256) void lstm_step_kernel(
    const float* __restrict__ x, int Kx,
    const float* __restrict__ w_ih,
    const float* __restrict__ h_prev,
    const float* __restrict__ w_hh,
    const float* __restrict__ bias,
    float* __restrict__ c_state,
    float* __restrict__ h_out,
    float* __restrict__ h_store, int h_store_stride)
{
    __shared__ __align__(16) float xM[64][68];        // [m][k], pad 68 (272B = 17*16 -> float4-aligned rows)
    __shared__ __align__(16) float gates_s[4][64][4]; // [gate][m][jl]

    const int tid = threadIdx.x;
    const int jb = blockIdx.x;
    const int j0 = jb * 4;
    const int m  = tid & 63;
    const int gi = tid >> 6;   // gate index 0..3 (i,f,g,o)

    float acc[4];
    #pragma unroll
    for (int jj = 0; jj < 4; jj++) acc[jj] = bias[gi * HH + j0 + jj];

    for (int phase = 0; phase < 2; ++phase) {
        const float* p = phase ? h_prev : x;
        const float* w = phase ? w_hh : w_ih;
        const int K = phase ? HH : Kx;
        for (int k0 = 0; k0 < K; k0 += 64) {
            int kc = K - k0; if (kc > 64) kc = 64;
            // stage chunk: xM[m][k] (zero-padded past kc)
            {
                int kk = tid & 63;
                int mq = tid >> 6;
                #pragma unroll
                for (int i = 0; i < 16; i++) {
                    int mm = mq * 16 + i;
                    xM[mm][kk] = (kk < kc) ? p[(long)mm * K + k0 + kk] : 0.0f;
                }
            }
            __syncthreads();
            int kcr = kc & ~3;
            for (int k = 0; k < kcr; k += 4) {
                float4 xv = *(const float4*)&xM[m][k];
                const float* wr = w + (long)(k0 + k) * G4 + gi * HH + j0;
                float4 w0 = *(const float4*)(wr);
                float4 w1 = *(const float4*)(wr + G4);
                float4 w2 = *(const float4*)(wr + 2 * G4);
                float4 w3 = *(const float4*)(wr + 3 * G4);
                acc[0] += xv.x * w0.x + xv.y * w1.x + xv.z * w2.x + xv.w * w3.x;
                acc[1] += xv.x * w0.y + xv.y * w1.y + xv.z * w2.y + xv.w * w3.y;
                acc[2] += xv.x * w0.z + xv.y * w1.z + xv.z * w2.z + xv.w * w3.z;
                acc[3] += xv.x * w0.w + xv.y * w1.w + xv.z * w2.w + xv.w * w3.w;
            }
            for (int k = kcr; k < kc; k++) {
                float xv = xM[m][k];
                const float* wr = w + (long)(k0 + k) * G4 + gi * HH + j0;
                acc[0] += xv * wr[0];
                acc[1] += xv * wr[1];
                acc[2] += xv * wr[2];
                acc[3] += xv * wr[3];
            }
            __syncthreads();
        }
    }

    // exchange gates through LDS
    *(float4*)&gates_s[gi][m][0] = make_float4(acc[0], acc[1], acc[2], acc[3]);
    __syncthreads();

    // elementwise LSTM update: thread -> (m2, jl)
    {
        int m2 = tid >> 2;
        int jl = tid & 3;
        float ig = gates_s[0][m2][jl];
        float fg = gates_s[1][m2][jl];
        float gg = gates_s[2][m2][jl];
        float og = gates_s[3][m2][jl];
        int idx = m2 * HH + j0 + jl;
        float cold = c_state[idx];
        float si = 1.0f / (1.0f + expf(-ig));
        float sf = 1.0f / (1.0f + expf(-fg));
        float so = 1.0f / (1.0f + expf(-og));
        float cn = sf * cold + si * tanhf(gg);
        float hn = so * tanhf(cn);
        c_state[idx] = cn;
        h_out[idx] = hn;
        if (h_store) h_store[(long)m2 * h_store_stride + j0 + jl] = hn;
    }
}

// ---------------- output GEMM: logits = H1 @ w_out + b_out ----------------
// A: 8128 x 1024 (rows b*127+t), Bw: 1024 x 10000, out: d_out+1 (8128 x 10000)
__global__ __launch_bounds__(256) void out_gemm_kernel(
    const float* __restrict__ A,
    const float* __restrict__ Bw,
    const float* __restrict__ bias,
    float* __restrict__ out)
{
    __shared__ __align__(16) float As[16][72];  // [k][r]
    __shared__ __align__(16) float Bs[16][72];  // [k][c]
    int bxN = blockIdx.x;   // 0..156
    int byM = blockIdx.y;   // 0..126
    int tid = threadIdx.x;
    int tn = tid & 15, tm = tid >> 4;
    int r0 = byM * 64, c0 = bxN * 64;
    float acc[4][4] = {};

    for (int k0 = 0; k0 < 1024; k0 += 16) {
        // stage A (64 rows x 16 k) -> As[k][r]
        {
            int k = tid & 15;
            int rr = tid >> 4;   // 0..15
            #pragma unroll
            for (int i = 0; i < 4; i++) {
                int r = rr + 16 * i;
                As[k][r] = A[(long)(r0 + r) * 1024 + k0 + k];
            }
        }
        // stage B (16 k x 64 c) -> Bs[k][c]
        {
            int c = tid & 63;
            int kq = tid >> 6;
            int cg = c0 + c;
            #pragma unroll
            for (int i = 0; i < 4; i++) {
                int k = kq * 4 + i;
                Bs[k][c] = (cg < VV) ? Bw[(long)(k0 + k) * VV + cg] : 0.0f;
            }
        }
        __syncthreads();
        #pragma unroll
        for (int kk = 0; kk < 16; kk++) {
            float4 av = *(const float4*)&As[kk][tm * 4];
            float4 bv = *(const float4*)&Bs[kk][tn * 4];
            float a4[4] = {av.x, av.y, av.z, av.w};
            float b4[4] = {bv.x, bv.y, bv.z, bv.w};
            #pragma unroll
            for (int i = 0; i < 4; i++)
                #pragma unroll
                for (int j = 0; j < 4; j++)
                    acc[i][j] += a4[i] * b4[j];
        }
        __syncthreads();
    }

    #pragma unroll
    for (int i = 0; i < 4; i++) {
        int r = r0 + tm * 4 + i;
        #pragma unroll
        for (int j = 0; j < 4; j++) {
            int c = c0 + tn * 4 + j;
            if (c < VV) out[(long)r * VV + c] = acc[i][j] + bias[c];
        }
    }
}

// ---------------- per-row log-softmax loss ----------------
// grid 8128 blocks; r = b*127+t; rowloss[r] = (gt==0) ? 0 : -(logit[gt]-max-log(sum))
__global__ __launch_bounds__(256) void loss_kernel(
    const float* __restrict__ logits,
    const int* __restrict__ sent,
    float* __restrict__ rowloss)
{
    __shared__ float red[256];
    int r = blockIdx.x;
    int b = r / TM1, t = r % TM1;
    const float* row = logits + (long)r * VV;
    int tid = threadIdx.x;

    float mx = -INFINITY;
    for (int v = tid; v < VV; v += 256) mx = fmaxf(mx, row[v]);
    red[tid] = mx; __syncthreads();
    for (int s = 128; s > 0; s >>= 1) {
        if (tid < s) red[tid] = fmaxf(red[tid], red[tid + s]);
        __syncthreads();
    }
    mx = red[0];
    __syncthreads();

    float sum = 0.0f;
    for (int v = tid; v < VV; v += 256) sum += expf(row[v] - mx);
    red[tid] = sum; __syncthreads();
    for (int s = 128; s > 0; s >>= 1) {
        if (tid < s) red[tid] += red[tid + s];
        __syncthreads();
    }
    if (tid == 0) {
        int gt = sent[b * TT + t + 1];
        float val = 0.0f;
        if (gt != 0) val = -(row[gt] - mx - logf(red[0]));
        rowloss[r] = val;
    }
}

// ---------------- final reduction: loss = sum_b ( sum_t rowloss ) / length[b] ----------------
__global__ void final_kernel(const float* __restrict__ rowloss,
                             const int* __restrict__ length,
                             float* __restrict__ out0)
{
    int b = threadIdx.x;   // 0..63
    float s = 0.0f;
    for (int t = 0; t < TM1; t++) s += rowloss[b * TM1 + t];
    s /= (float)length[b];
    #pragma unroll
    for (int off = 32; off > 0; off >>= 1) s += __shfl_down(s, off, 64);
    if (b == 0) out0[0] = s;
}

extern "C" void kernel_launch(void* const* d_in, const int* in_sizes, int n_in,
                              void* d_out, int out_size, void* d_ws, size_t ws_size,
                              hipStream_t stream) {
    const int*   sent    = (const int*)d_in[0];
    const int*   length  = (const int*)d_in[1];
    const float* wordvec = (const float*)d_in[2];
    const float* w_ih0   = (const float*)d_in[3];
    const float* w_hh0   = (const float*)d_in[4];
    const float* b0      = (const float*)d_in[5];
    const float* w_ih1   = (const float*)d_in[6];
    const float* w_hh1   = (const float*)d_in[7];
    const float* b1      = (const float*)d_in[8];
    const float* w_out   = (const float*)d_in[9];
    const float* b_out   = (const float*)d_in[10];
    float* out = (float*)d_out;

    float* ws  = (float*)d_ws;
    float* X   = ws;                               // 127*64*300 = 2438400
    float* H1  = X + 2438400;                      // 8128*1024  = 8323072
    float* h0a = H1 + 8323072;
    float* h0b = h0a + 64 * 1024;
    float* c0  = h0b + 64 * 1024;
    float* h1a = c0  + 64 * 1024;
    float* h1b = h1a + 64 * 1024;
    float* c1  = h1b + 64 * 1024;
    float* rowloss = c1 + 64 * 1024;               // 8128

    // zero h0a, h0b, c0, h1a, h1b, c1 (contiguous 6*65536)
    {
        int n = 6 * 64 * 1024;
        zero_kernel<<<(n + 255) / 256, 256, 0, stream>>>(h0a, n);
    }
    embed_kernel<<<TM1 * BB, 256, 0, stream>>>(sent, wordvec, X);

    for (int t = 0; t < TM1; t++) {
        float* h0p = (t & 1) ? h0b : h0a;
        float* h0n = (t & 1) ? h0a : h0b;
        float* h1p = (t & 1) ? h1b : h1a;
        float* h1n = (t & 1) ? h1a : h1b;
        lstm_step_kernel<<<256, 256, 0, stream>>>(
            X + (long)t * 64 * EE, EE, w_ih0, h0p, w_hh0, b0, c0, h0n, nullptr, 0);
        lstm_step_kernel<<<256, 256, 0, stream>>>(
            h0n, HH, w_ih1, h1p, w_hh1, b1, c1, h1n, H1 + (long)t * 1024, TM1 * 1024);
    }

    out_gemm_kernel<<<dim3(157, 127), 256, 0, stream>>>(H1, w_out, b_out, out + 1);
    loss_kernel<<<TM1 * BB, 256, 0, stream>>>(out + 1, sent, rowloss);
    final_kernel<<<1, 64, 0, stream>>>(rowloss, length, out);
}

// Round 2
// 4581.305 us; speedup vs baseline: 13.5730x; 13.5730x over previous
//
#include <hip/hip_runtime.h>
#include <hip/hip_bf16.h>
#include <math.h>

#define BB 64
#define TT 128
#define VV 10000
#define EE 300
#define HH 1024
#define TM1 127

typedef __hip_bfloat16 bf16;
typedef __attribute__((ext_vector_type(8))) short s8v;   // 8 bf16 = 4 VGPRs (MFMA A/B frag)
typedef __attribute__((ext_vector_type(4))) float f4v;   // 4 fp32 (MFMA C/D frag)

// ---------------- zero ----------------
__global__ void zero_kernel(float* __restrict__ p, int n) {
    int i = blockIdx.x * blockDim.x + threadIdx.x;
    if (i < n) p[i] = 0.0f;
}

// ---------------- embedding gather -> bf16, padded [128*64][320] ----------------
__global__ void embed_kernel(const int* __restrict__ sent,
                             const float* __restrict__ wordvec,
                             bf16* __restrict__ X) {
    int bi = blockIdx.x;          // t*64+b, t in [0,128)
    int t = bi >> 6;
    int b = bi & 63;
    int w = (t < TM1) ? sent[b * TT + t] : 0;
    const float* src = wordvec + (long)w * EE;
    bf16* dst = X + (long)bi * 320;
    for (int e = threadIdx.x; e < 320; e += 64) {
        float v = (t < TM1 && e < EE) ? src[e] : 0.0f;
        dst[e] = __float2bfloat16(v);
    }
}

// ---------------- transpose+convert: src fp32 [K][N] -> dst bf16 [Nrows][Kpad] ----------------
// grid (Nrows/32, Kpad/32), 256 threads. Pads (k>=K or n>=N) are zero-filled.
__global__ void transpose_bf16_kernel(const float* __restrict__ src,
                                      bf16* __restrict__ dst,
                                      int K, int N, int Kpad) {
    __shared__ float tile[32][33];
    int n0 = blockIdx.x * 32, k0 = blockIdx.y * 32;
    int tid = threadIdx.x;
    {
        int tn = tid & 31, tk = tid >> 5;
        #pragma unroll
        for (int i = 0; i < 4; i++) {
            int k = tk + i * 8;
            float v = (k0 + k < K && n0 + tn < N) ? src[(long)(k0 + k) * N + n0 + tn] : 0.0f;
            tile[k][tn] = v;
        }
    }
    __syncthreads();
    {
        int wk = tid & 31, wn = tid >> 5;
        #pragma unroll
        for (int i = 0; i < 4; i++) {
            int n = wn + i * 8;
            dst[(long)(n0 + n) * Kpad + k0 + wk] = __float2bfloat16(tile[wk][n]);
        }
    }
}

// ---------------- fused LSTM step (MFMA) ----------------
// Block (phase, r, j): 16 batch rows (r*16..) x 16 hidden cols (j*16..), all 4 gates
// (wave g = gate g). Phase A computes layer0 for step ta: g0 = x(ta)@w_ih0 + h0@w_hh0 + b0.
// Phase B computes layer1 for step tb: g1 = h0@w_ih1 + h1@w_hh1 + b1, stores H1.
// j = bid&63 so the 4 row-split blocks of a weight slice share an XCD (bid%8) -> L2-resident.
__global__ __launch_bounds__(256) void step_kernel(
    const bf16* __restrict__ X, int ta, int tb, int a_only,
    const bf16* __restrict__ h0_in, bf16* __restrict__ h0_out,
    const bf16* __restrict__ h1_in, bf16* __restrict__ h1_out,
    const bf16* __restrict__ wt_ih0, const bf16* __restrict__ wt_hh0,
    const bf16* __restrict__ wt_ih1, const bf16* __restrict__ wt_hh1,
    const float* __restrict__ b0, const float* __restrict__ b1,
    float* __restrict__ c0, float* __restrict__ c1,
    bf16* __restrict__ H1)
{
    __shared__ float gbuf[4][16][17];
    int bid = blockIdx.x;
    int isA, pb;
    if (a_only) { isA = 1; pb = bid; }
    else        { isA = (bid >= 256); pb = bid & 255; }
    const int j = pb & 63, r = pb >> 6;
    const int tid = threadIdx.x;
    const int g = tid >> 6, L = tid & 63, quad = L >> 4, l16 = L & 15;

    const int arow = r * 16 + l16;             // batch row this lane's A-frag covers
    const int wrow = g * HH + j * 16 + l16;    // transposed-weight row (output col)

    f4v acc0 = {0.f, 0.f, 0.f, 0.f};
    f4v acc1 = {0.f, 0.f, 0.f, 0.f};

    if (isA) {
        // segment 1: x(ta) @ w_ih0, K=320 (padded 300)
        const s8v* ax = (const s8v*)(X + ((long)(ta * 64 + arow)) * 320 + quad * 8);
        const s8v* bx = (const s8v*)(wt_ih0 + (long)wrow * 320 + quad * 8);
        #pragma unroll
        for (int k = 0; k < 10; k++) {
            if (k & 1) acc1 = __builtin_amdgcn_mfma_f32_16x16x32_bf16(ax[k*4], bx[k*4], acc1, 0, 0, 0);
            else       acc0 = __builtin_amdgcn_mfma_f32_16x16x32_bf16(ax[k*4], bx[k*4], acc0, 0, 0, 0);
        }
        // segment 2: h0 @ w_hh0, K=1024
        const s8v* ah = (const s8v*)(h0_in + (long)arow * HH + quad * 8);
        const s8v* bh = (const s8v*)(wt_hh0 + (long)wrow * HH + quad * 8);
        #pragma unroll
        for (int k = 0; k < 32; k++) {
            if (k & 1) acc1 = __builtin_amdgcn_mfma_f32_16x16x32_bf16(ah[k*4], bh[k*4], acc1, 0, 0, 0);
            else       acc0 = __builtin_amdgcn_mfma_f32_16x16x32_bf16(ah[k*4], bh[k*4], acc0, 0, 0, 0);
        }
    } else {
        // segment 1: h0(tb) @ w_ih1
        const s8v* a0 = (const s8v*)(h0_in + (long)arow * HH + quad * 8);
        const s8v* b0f = (const s8v*)(wt_ih1 + (long)wrow * HH + quad * 8);
        #pragma unroll
        for (int k = 0; k < 32; k++) {
            if (k & 1) acc1 = __builtin_amdgcn_mfma_f32_16x16x32_bf16(a0[k*4], b0f[k*4], acc1, 0, 0, 0);
            else       acc0 = __builtin_amdgcn_mfma_f32_16x16x32_bf16(a0[k*4], b0f[k*4], acc0, 0, 0, 0);
        }
        // segment 2: h1(tb-1) @ w_hh1
        const s8v* a1 = (const s8v*)(h1_in + (long)arow * HH + quad * 8);
        const s8v* b1f = (const s8v*)(wt_hh1 + (long)wrow * HH + quad * 8);
        #pragma unroll
        for (int k = 0; k < 32; k++) {
            if (k & 1) acc1 = __builtin_amdgcn_mfma_f32_16x16x32_bf16(a1[k*4], b1f[k*4], acc1, 0, 0, 0);
            else       acc0 = __builtin_amdgcn_mfma_f32_16x16x32_bf16(a1[k*4], b1f[k*4], acc0, 0, 0, 0);
        }
    }
    acc0 += acc1;

    // C/D layout: col=lane&15, row=quad*4+reg
    #pragma unroll
    for (int i = 0; i < 4; i++) gbuf[g][quad * 4 + i][l16] = acc0[i];
    __syncthreads();

    // elementwise LSTM update: thread -> one (row,col) of the 16x16 tile
    {
        int row = tid >> 4, col = tid & 15;
        int hrow = r * 16 + row, hcol = j * 16 + col;
        const float* bias = isA ? b0 : b1;
        float gi = gbuf[0][row][col] + bias[hcol];
        float gf = gbuf[1][row][col] + bias[HH + hcol];
        float gg = gbuf[2][row][col] + bias[2 * HH + hcol];
        float go = gbuf[3][row][col] + bias[3 * HH + hcol];
        float* cst = isA ? c0 : c1;
        int idx = hrow * HH + hcol;
        float c = cst[idx];
        float si = 1.0f / (1.0f + expf(-gi));
        float sf = 1.0f / (1.0f + expf(-gf));
        float so = 1.0f / (1.0f + expf(-go));
        float cn = sf * c + si * tanhf(gg);
        float hn = so * tanhf(cn);
        cst[idx] = cn;
        bf16 hb = __float2bfloat16(hn);
        if (isA) h0_out[idx] = hb;
        else {
            h1_out[idx] = hb;
            H1[((long)hrow * TM1 + tb) * HH + hcol] = hb;
        }
    }
}

// ---------------- output GEMM (MFMA): out = H1 @ w_out + b_out ----------------
// H1 bf16 [8192][1024] (rows b*127+t, pad rows unused), Wt bf16 [10112][1024]
// block tile 128x128, 4 waves in 2x2, each wave 64x64 = 4x4 MFMA tiles
__global__ __launch_bounds__(256) void out_gemm_mfma(
    const bf16* __restrict__ A, const bf16* __restrict__ Wt,
    const float* __restrict__ bias, float* __restrict__ out)
{
    int tid = threadIdx.x, w = tid >> 6, L = tid & 63, quad = L >> 4, l16 = L & 15;
    int wr = w >> 1, wc = w & 1;
    long R0 = (long)blockIdx.y * 128 + wr * 64;
    long C0 = (long)blockIdx.x * 128 + wc * 64;

    f4v acc[4][4] = {};
    const s8v* ap[4];
    const s8v* bp[4];
    #pragma unroll
    for (int i = 0; i < 4; i++) ap[i] = (const s8v*)(A + (R0 + i * 16 + l16) * 1024 + quad * 8);
    #pragma unroll
    for (int jj = 0; jj < 4; jj++) bp[jj] = (const s8v*)(Wt + (C0 + jj * 16 + l16) * 1024 + quad * 8);

    for (int k = 0; k < 32; k++) {
        s8v av[4], bv[4];
        #pragma unroll
        for (int i = 0; i < 4; i++) av[i] = ap[i][k * 4];
        #pragma unroll
        for (int jj = 0; jj < 4; jj++) bv[jj] = bp[jj][k * 4];
        #pragma unroll
        for (int i = 0; i < 4; i++)
            #pragma unroll
            for (int jj = 0; jj < 4; jj++)
                acc[i][jj] = __builtin_amdgcn_mfma_f32_16x16x32_bf16(av[i], bv[jj], acc[i][jj], 0, 0, 0);
    }

    #pragma unroll
    for (int i = 0; i < 4; i++) {
        #pragma unroll
        for (int jj = 0; jj < 4; jj++) {
            #pragma unroll
            for (int p = 0; p < 4; p++) {
                long row = R0 + i * 16 + quad * 4 + p;
                long col = C0 + jj * 16 + l16;
                if (row < 8128 && col < VV)
                    out[row * VV + col] = acc[i][jj][p] + bias[col];
            }
        }
    }
}

// ---------------- per-row log-softmax loss ----------------
__global__ __launch_bounds__(256) void loss_kernel(
    const float* __restrict__ logits,
    const int* __restrict__ sent,
    float* __restrict__ rowloss)
{
    __shared__ float red[256];
    int r = blockIdx.x;
    int b = r / TM1, t = r % TM1;
    const float* row = logits + (long)r * VV;
    int tid = threadIdx.x;

    float mx = -INFINITY;
    for (int v = tid; v < VV; v += 256) mx = fmaxf(mx, row[v]);
    red[tid] = mx; __syncthreads();
    for (int s = 128; s > 0; s >>= 1) {
        if (tid < s) red[tid] = fmaxf(red[tid], red[tid + s]);
        __syncthreads();
    }
    mx = red[0];
    __syncthreads();

    float sum = 0.0f;
    for (int v = tid; v < VV; v += 256) sum += expf(row[v] - mx);
    red[tid] = sum; __syncthreads();
    for (int s = 128; s > 0; s >>= 1) {
        if (tid < s) red[tid] += red[tid + s];
        __syncthreads();
    }
    if (tid == 0) {
        int gt = sent[b * TT + t + 1];
        float val = 0.0f;
        if (gt != 0) val = -(row[gt] - mx - logf(red[0]));
        rowloss[r] = val;
    }
}

__global__ void final_kernel(const float* __restrict__ rowloss,
                             const int* __restrict__ length,
                             float* __restrict__ out0)
{
    int b = threadIdx.x;   // 0..63
    float s = 0.0f;
    for (int t = 0; t < TM1; t++) s += rowloss[b * TM1 + t];
    s /= (float)length[b];
    #pragma unroll
    for (int off = 32; off > 0; off >>= 1) s += __shfl_down(s, off, 64);
    if (b == 0) out0[0] = s;
}

extern "C" void kernel_launch(void* const* d_in, const int* in_sizes, int n_in,
                              void* d_out, int out_size, void* d_ws, size_t ws_size,
                              hipStream_t stream) {
    const int*   sent    = (const int*)d_in[0];
    const int*   length  = (const int*)d_in[1];
    const float* wordvec = (const float*)d_in[2];
    const float* w_ih0   = (const float*)d_in[3];
    const float* w_hh0   = (const float*)d_in[4];
    const float* b0      = (const float*)d_in[5];
    const float* w_ih1   = (const float*)d_in[6];
    const float* w_hh1   = (const float*)d_in[7];
    const float* b1      = (const float*)d_in[8];
    const float* w_out   = (const float*)d_in[9];
    const float* b_out   = (const float*)d_in[10];
    float* out = (float*)d_out;

    char* W = (char*)d_ws;
    size_t o = 0;
    bf16* X      = (bf16*)(W + o); o += 128L * 64 * 320 * 2;        // 5,242,880
    bf16* wtih0  = (bf16*)(W + o); o += 4096L * 320 * 2;            // 2,621,440
    bf16* wthh0  = (bf16*)(W + o); o += 4096L * 1024 * 2;           // 8,388,608
    bf16* wtih1  = (bf16*)(W + o); o += 4096L * 1024 * 2;
    bf16* wthh1  = (bf16*)(W + o); o += 4096L * 1024 * 2;
    bf16* woutt  = (bf16*)(W + o); o += 10112L * 1024 * 2;          // 20,709,376
    bf16* H1     = (bf16*)(W + o); o += 8192L * 1024 * 2;           // 16,777,216
    // zero region (contiguous): h0b0, h1b0, c0, c1
    bf16*  h0b0  = (bf16*)(W + o); o += 64L * 1024 * 2;
    bf16*  h1b0  = (bf16*)(W + o); o += 64L * 1024 * 2;
    float* c0    = (float*)(W + o); o += 64L * 1024 * 4;
    float* c1    = (float*)(W + o); o += 64L * 1024 * 4;
    bf16*  h0b1  = (bf16*)(W + o); o += 64L * 1024 * 2;
    bf16*  h1b1  = (bf16*)(W + o); o += 64L * 1024 * 2;
    float* rowloss = (float*)(W + o); o += 8128L * 4;

    // zero h0b0,h1b0,c0,c1 = 786432 B = 196608 floats
    zero_kernel<<<768, 256, 0, stream>>>((float*)h0b0, 196608);
    embed_kernel<<<128 * 64, 64, 0, stream>>>(sent, wordvec, X);
    transpose_bf16_kernel<<<dim3(128, 10), 256, 0, stream>>>(w_ih0, wtih0, 300, 4096, 320);
    transpose_bf16_kernel<<<dim3(128, 32), 256, 0, stream>>>(w_hh0, wthh0, 1024, 4096, 1024);
    transpose_bf16_kernel<<<dim3(128, 32), 256, 0, stream>>>(w_ih1, wtih1, 1024, 4096, 1024);
    transpose_bf16_kernel<<<dim3(128, 32), 256, 0, stream>>>(w_hh1, wthh1, 1024, 4096, 1024);
    transpose_bf16_kernel<<<dim3(316, 32), 256, 0, stream>>>(w_out, woutt, 1024, VV, 1024);

    // A-only: layer0 step 0 (h0_prev = zeros in h0b0) -> h0(0) in h0b1
    step_kernel<<<256, 256, 0, stream>>>(
        X, 0, 0, 1,
        h0b0, h0b1, h1b0, h1b1,
        wtih0, wthh0, wtih1, wthh1, b0, b1, c0, c1, H1);

    // combo steps: B(t) uses h0(t), h1(t-1); A(t+1) uses x(t+1), h0(t)
    for (int t = 0; t < TM1; t++) {
        bf16* h0in  = (t & 1) ? h0b0 : h0b1;
        bf16* h0out = (t & 1) ? h0b1 : h0b0;
        bf16* h1in  = (t & 1) ? h1b1 : h1b0;
        bf16* h1out = (t & 1) ? h1b0 : h1b1;
        step_kernel<<<512, 256, 0, stream>>>(
            X, t + 1, t, 0,
            h0in, h0out, h1in, h1out,
            wtih0, wthh0, wtih1, wthh1, b0, b1, c0, c1, H1);
    }

    out_gemm_mfma<<<dim3(79, 64), 256, 0, stream>>>(H1, woutt, b_out, out + 1);
    loss_kernel<<<TM1 * BB, 256, 0, stream>>>(out + 1, sent, rowloss);
    final_kernel<<<1, 64, 0, stream>>>(rowloss, length, out);
}